// Round 2
// baseline (1554.087 us; speedup 1.0000x reference)
//
#include <hip/hip_runtime.h>
#include <math.h>

#define NEG_SLOPE 0.2f

__device__ __forceinline__ float lrelu(float x){ return x > 0.f ? x : NEG_SLOPE * x; }

// ---------------- transform: xs = A @ W ; fused a_src/a_dst epilogue ----------------
template<int K>
__global__ void transform_kernel(const float* __restrict__ A, const float* __restrict__ W,
                                 const float* __restrict__ att_s, const float* __restrict__ att_d,
                                 float* __restrict__ xs, float* __restrict__ a_src,
                                 float* __restrict__ a_dst, int N){
  int n = blockIdx.x;          // one node per block
  int j = threadIdx.x;         // 0..127 output channel
  __shared__ float sA[K];
  __shared__ float s_s[128], s_d[128];
  if (j < K) sA[j] = A[(size_t)n * K + j];
  __syncthreads();
  float acc = 0.f;
  #pragma unroll
  for (int k = 0; k < K; ++k) acc += sA[k] * W[k * 128 + j];
  xs[(size_t)n * 128 + j] = acc;
  s_s[j] = acc * att_s[j];
  s_d[j] = acc * att_d[j];
  __syncthreads();
  if (j < 4){
    float ss = 0.f, sd = 0.f;
    #pragma unroll
    for (int c = 0; c < 32; ++c){ ss += s_s[j*32 + c]; sd += s_d[j*32 + c]; }
    a_src[n*4 + j] = ss;
    a_dst[n*4 + j] = sd;
  }
}

// ---------------- CSR build ----------------
__global__ void count_kernel(const int* __restrict__ ei, int E, int* __restrict__ cnt){
  int e = blockIdx.x * blockDim.x + threadIdx.x;
  if (e < E) atomicAdd(&cnt[ei[E + e]], 1);   // row 1 = dst
}

__global__ void scan_kernel(const int* __restrict__ cnt, int N, int* __restrict__ rp){
  const int tid = threadIdx.x;
  const int lane = tid & 63;
  const int wv = tid >> 6;              // 0..15 (1024 threads)
  __shared__ int wsum[16];
  __shared__ int carry;
  if (tid == 0){ carry = 0; rp[0] = 0; }
  __syncthreads();
  for (int base = 0; base < N; base += 1024){
    int idx = base + tid;
    int v = (idx < N) ? cnt[idx] : 0;
    int x = v;
    #pragma unroll
    for (int d = 1; d < 64; d <<= 1){
      int y = __shfl_up(x, d);
      if (lane >= d) x += y;
    }
    if (lane == 63) wsum[wv] = x;
    __syncthreads();
    if (tid < 16){
      int y = wsum[tid];
      #pragma unroll
      for (int d = 1; d < 16; d <<= 1){
        int z = __shfl_up(y, d);
        if (tid >= d) y += z;
      }
      wsum[tid] = y;                    // inclusive over wave sums
    }
    __syncthreads();
    int off = carry + (wv > 0 ? wsum[wv-1] : 0);
    int incl = off + x;
    if (idx < N) rp[idx + 1] = incl;
    __syncthreads();
    if (tid == 1023) carry = incl;      // chunk total (tail lanes add 0)
    __syncthreads();
  }
}

__global__ void fill_kernel(const int* __restrict__ ei, const float* __restrict__ eattr, int E,
                            const int* __restrict__ rp, int* __restrict__ fc,
                            int* __restrict__ csrc, float* __restrict__ cea){
  int e = blockIdx.x * blockDim.x + threadIdx.x;
  if (e >= E) return;
  int src = ei[e];
  int dst = ei[E + e];
  int pos = rp[dst] + atomicAdd(&fc[dst], 1);
  csrc[pos] = src;
  if (eattr) cea[pos] = eattr[e];
}

__global__ void loopea_kernel(const int* __restrict__ rp, const float* __restrict__ cea,
                              float* __restrict__ lea, int N){
  int n = blockIdx.x * blockDim.x + threadIdx.x;
  if (n >= N) return;
  int b = rp[n], e = rp[n+1];
  float s = 0.f;
  for (int i = b; i < e; ++i) s += cea[i];
  lea[n] = s / fmaxf((float)(e - b), 1.f);
}

__global__ void coef_kernel(const float* __restrict__ We1, const float* __restrict__ ae1,
                            const float* __restrict__ We2, const float* __restrict__ ae2,
                            float* __restrict__ coef){
  int t = threadIdx.x;
  if (t < 4){
    float s = 0.f;
    for (int c = 0; c < 32; ++c) s += We1[t*32 + c] * ae1[t*32 + c];
    coef[t] = s;
  } else if (t < 8){
    int h = t - 4;
    float s = 0.f;
    for (int c = 0; c < 32; ++c) s += We2[h*32 + c] * ae2[h*32 + c];
    coef[4 + h] = s;
  }
}

// ---------------- GAT per-node kernel: one wave per node ----------------
template<bool HASE, bool RELU>
__global__ void gat_kernel(const int* __restrict__ rp, const int* __restrict__ csrc,
                           const float* __restrict__ cea, const float* __restrict__ loopea,
                           const float* __restrict__ coef,
                           const float* __restrict__ xs, const float* __restrict__ a_src,
                           const float* __restrict__ a_dst, const float* __restrict__ bias,
                           float* __restrict__ out, int N){
  const int wv = threadIdx.x >> 6;
  const int lane = threadIdx.x & 63;
  const int n = blockIdx.x * 4 + wv;
  if (n >= N) return;

  const int beg = rp[n], end = rp[n+1];
  const int deg = end - beg;

  const float4 adv = *reinterpret_cast<const float4*>(a_dst + (size_t)n*4);
  const float4 asv = *reinterpret_cast<const float4*>(a_src + (size_t)n*4);
  float c0 = 0.f, c1 = 0.f, c2 = 0.f, c3 = 0.f, lea = 0.f;
  if (HASE){ c0 = coef[0]; c1 = coef[1]; c2 = coef[2]; c3 = coef[3]; lea = loopea[n]; }

  // self-loop alpha (pre-softmax)
  const float s0 = lrelu(asv.x + adv.x + lea*c0);
  const float s1 = lrelu(asv.y + adv.y + lea*c1);
  const float s2 = lrelu(asv.z + adv.z + lea*c2);
  const float s3 = lrelu(asv.w + adv.w + lea*c3);

  // -------- phase 1: per-head max over incoming edges (lane-parallel) --------
  float m0 = s0, m1 = s1, m2 = s2, m3 = s3;
  for (int i = lane; i < deg; i += 64){
    int s = csrc[beg + i];
    float ea = HASE ? cea[beg + i] : 0.f;
    const float4 av = *reinterpret_cast<const float4*>(a_src + (size_t)s*4);
    m0 = fmaxf(m0, lrelu(av.x + adv.x + ea*c0));
    m1 = fmaxf(m1, lrelu(av.y + adv.y + ea*c1));
    m2 = fmaxf(m2, lrelu(av.z + adv.z + ea*c2));
    m3 = fmaxf(m3, lrelu(av.w + adv.w + ea*c3));
  }
  #pragma unroll
  for (int d = 1; d < 64; d <<= 1){
    m0 = fmaxf(m0, __shfl_xor(m0, d));
    m1 = fmaxf(m1, __shfl_xor(m1, d));
    m2 = fmaxf(m2, __shfl_xor(m2, d));
    m3 = fmaxf(m3, __shfl_xor(m3, d));
  }

  // -------- phase 2: fused exp + denom + aggregation --------
  const int c = lane * 2;           // this lane owns channels c, c+1
  const int h = c >> 5;             // head of those channels
  const float mh  = (h==0) ? m0 : (h==1) ? m1 : (h==2) ? m2 : m3;
  const float adh = (h==0) ? adv.x : (h==1) ? adv.y : (h==2) ? adv.z : adv.w;
  const float ch  = (h==0) ? c0 : (h==1) ? c1 : (h==2) ? c2 : c3;
  const float sh  = (h==0) ? s0 : (h==1) ? s1 : (h==2) ? s2 : s3;

  float ps = expf(sh - mh);
  float denom = ps;
  float2 selfv = *reinterpret_cast<const float2*>(xs + (size_t)n*128 + c);
  float accx = ps * selfv.x;
  float accy = ps * selfv.y;

  for (int i = 0; i < deg; ++i){
    int s = csrc[beg + i];                       // uniform across lanes
    float ea = HASE ? cea[beg + i] : 0.f;
    float a = a_src[(size_t)s*4 + h];
    float al = lrelu(a + adh + ea*ch);
    float p = expf(al - mh);
    denom += p;
    float2 v = *reinterpret_cast<const float2*>(xs + (size_t)s*128 + c);
    accx += p * v.x;
    accy += p * v.y;
  }

  const float inv = 1.f / (denom + 1e-16f);
  float ox = accx * inv + bias[c];
  float oy = accy * inv + bias[c+1];
  if (RELU){ ox = fmaxf(ox, 0.f); oy = fmaxf(oy, 0.f); }
  out[(size_t)n*128 + c]     = ox;
  out[(size_t)n*128 + c + 1] = oy;
}

// ---------------- pooling + head ----------------
__global__ void pool_kernel(const float* __restrict__ a, const int* __restrict__ batch,
                            float* __restrict__ sums, int* __restrict__ cnts, int N){
  int idx = blockIdx.x * blockDim.x + threadIdx.x;
  if (idx >= N * 128) return;
  int n = idx >> 7, cch = idx & 127;
  int g = batch[n];
  atomicAdd(&sums[g*128 + cch], 0.5f * a[idx]);
  if (cch == 0 && cnts) atomicAdd(&cnts[g], 1);
}

__global__ void head_kernel(const float* __restrict__ sums, const int* __restrict__ cnts,
                            const float* __restrict__ ffW, const float* __restrict__ ffb,
                            const float* __restrict__ outW, const float* __restrict__ outb,
                            float* __restrict__ out){
  int g = blockIdx.x, j = threadIdx.x;   // 64 blocks x 128 threads
  __shared__ float mean[128];
  __shared__ float red[128];
  float cnt = fmaxf((float)cnts[g], 1.f);
  mean[j] = sums[g*128 + j] / cnt;
  __syncthreads();
  float acc = ffb[j];
  #pragma unroll 8
  for (int k = 0; k < 128; ++k) acc += mean[k] * ffW[k*128 + j];
  acc = fmaxf(acc, 0.f);
  red[j] = acc * outW[j];
  __syncthreads();
  for (int s = 64; s > 0; s >>= 1){
    if (j < s) red[j] += red[j + s];
    __syncthreads();
  }
  if (j == 0) out[g] = 1.f / (1.f + expf(-(red[0] + outb[0])));
}

// ---------------- host launch ----------------
extern "C" void kernel_launch(void* const* d_in, const int* in_sizes, int n_in,
                              void* d_out, int out_size, void* d_ws, size_t ws_size,
                              hipStream_t stream) {
  const float* x     = (const float*)d_in[0];
  const int*   cov   = (const int*)d_in[1];
  const int*   dist  = (const int*)d_in[2];
  const float* dattr = (const float*)d_in[3];
  const int*   batch = (const int*)d_in[4];
  const float* W_c1 = (const float*)d_in[5],  *as_c1 = (const float*)d_in[6],
             *ad_c1 = (const float*)d_in[7],  *b_c1  = (const float*)d_in[8];
  const float* W_c2 = (const float*)d_in[9],  *as_c2 = (const float*)d_in[10],
             *ad_c2 = (const float*)d_in[11], *b_c2  = (const float*)d_in[12];
  const float* W_d1 = (const float*)d_in[13], *as_d1 = (const float*)d_in[14],
             *ad_d1 = (const float*)d_in[15], *b_d1  = (const float*)d_in[16];
  const float* W_d2 = (const float*)d_in[17], *as_d2 = (const float*)d_in[18],
             *ad_d2 = (const float*)d_in[19], *b_d2  = (const float*)d_in[20];
  const float* We_d1 = (const float*)d_in[21], *ae_d1 = (const float*)d_in[22];
  const float* We_d2 = (const float*)d_in[23], *ae_d2 = (const float*)d_in[24];
  const float* ffW = (const float*)d_in[25], *ffb = (const float*)d_in[26];
  const float* outW = (const float*)d_in[27], *outb = (const float*)d_in[28];
  float* out = (float*)d_out;

  const int N  = in_sizes[0] / 32;
  const int Ec = in_sizes[1] / 2;
  const int Ed = in_sizes[2] / 2;

  char* p = (char*)d_ws;
  auto alloc = [&](size_t bytes) -> void* {
    void* r = (void*)p;
    p += (bytes + 255) & ~(size_t)255;
    return r;
  };
  float* act    = (float*)alloc((size_t)N * 128 * 4);
  float* xs     = (float*)alloc((size_t)N * 128 * 4);
  float* a_s    = (float*)alloc((size_t)N * 4 * 4);
  float* a_d    = (float*)alloc((size_t)N * 4 * 4);
  int*   rp_c   = (int*)alloc((size_t)(N + 1) * 4);
  int*   rp_d   = (int*)alloc((size_t)(N + 1) * 4);
  int*   csrc_c = (int*)alloc((size_t)Ec * 4);
  int*   csrc_d = (int*)alloc((size_t)Ed * 4);
  float* cea_d  = (float*)alloc((size_t)Ed * 4);
  int*   cnt    = (int*)alloc((size_t)N * 4);
  float* lea    = (float*)alloc((size_t)N * 4);
  float* coef   = (float*)alloc(8 * 4);
  float* sums   = (float*)alloc(64 * 128 * 4);
  int*   cnts   = (int*)alloc(64 * 4);

  const int TB = 256;
  // ---- covalent CSR ----
  hipMemsetAsync(cnt, 0, (size_t)N * 4, stream);
  count_kernel<<<(Ec + TB - 1) / TB, TB, 0, stream>>>(cov, Ec, cnt);
  scan_kernel<<<1, 1024, 0, stream>>>(cnt, N, rp_c);
  hipMemsetAsync(cnt, 0, (size_t)N * 4, stream);
  fill_kernel<<<(Ec + TB - 1) / TB, TB, 0, stream>>>(cov, nullptr, Ec, rp_c, cnt, csrc_c, nullptr);
  // ---- distance CSR ----
  hipMemsetAsync(cnt, 0, (size_t)N * 4, stream);
  count_kernel<<<(Ed + TB - 1) / TB, TB, 0, stream>>>(dist, Ed, cnt);
  scan_kernel<<<1, 1024, 0, stream>>>(cnt, N, rp_d);
  hipMemsetAsync(cnt, 0, (size_t)N * 4, stream);
  fill_kernel<<<(Ed + TB - 1) / TB, TB, 0, stream>>>(dist, dattr, Ed, rp_d, cnt, csrc_d, cea_d);
  loopea_kernel<<<(N + TB - 1) / TB, TB, 0, stream>>>(rp_d, cea_d, lea, N);
  coef_kernel<<<1, 64, 0, stream>>>(We_d1, ae_d1, We_d2, ae_d2, coef);

  hipMemsetAsync(sums, 0, 64 * 128 * 4, stream);
  hipMemsetAsync(cnts, 0, 64 * 4, stream);

  const int gatGrid = (N + 3) / 4;
  // ---- covalent branch ----
  transform_kernel<32><<<N, 128, 0, stream>>>(x, W_c1, as_c1, ad_c1, xs, a_s, a_d, N);
  gat_kernel<false, true><<<gatGrid, 256, 0, stream>>>(rp_c, csrc_c, nullptr, nullptr, nullptr,
                                                       xs, a_s, a_d, b_c1, act, N);
  transform_kernel<128><<<N, 128, 0, stream>>>(act, W_c2, as_c2, ad_c2, xs, a_s, a_d, N);
  gat_kernel<false, false><<<gatGrid, 256, 0, stream>>>(rp_c, csrc_c, nullptr, nullptr, nullptr,
                                                        xs, a_s, a_d, b_c2, act, N);
  pool_kernel<<<((size_t)N * 128 + TB - 1) / TB, TB, 0, stream>>>(act, batch, sums, cnts, N);
  // ---- distance branch ----
  transform_kernel<32><<<N, 128, 0, stream>>>(x, W_d1, as_d1, ad_d1, xs, a_s, a_d, N);
  gat_kernel<true, true><<<gatGrid, 256, 0, stream>>>(rp_d, csrc_d, cea_d, lea, coef,
                                                      xs, a_s, a_d, b_d1, act, N);
  transform_kernel<128><<<N, 128, 0, stream>>>(act, W_d2, as_d2, ad_d2, xs, a_s, a_d, N);
  gat_kernel<true, false><<<gatGrid, 256, 0, stream>>>(rp_d, csrc_d, cea_d, lea, coef + 4,
                                                       xs, a_s, a_d, b_d2, act, N);
  pool_kernel<<<((size_t)N * 128 + TB - 1) / TB, TB, 0, stream>>>(act, batch, sums, nullptr, N);
  // ---- head ----
  head_kernel<<<64, 128, 0, stream>>>(sums, cnts, ffW, ffb, outW, outb, out);
}

// Round 3
// 1172.290 us; speedup vs baseline: 1.3257x; 1.3257x over previous
//
#include <hip/hip_runtime.h>
#include <math.h>

#define NEG_SLOPE 0.2f

__device__ __forceinline__ float lrelu(float x){ return x > 0.f ? x : NEG_SLOPE * x; }

// ---------------- transform: xs = A @ W ; fused a_src/a_dst epilogue ----------------
template<int K>
__global__ void transform_kernel(const float* __restrict__ A, const float* __restrict__ W,
                                 const float* __restrict__ att_s, const float* __restrict__ att_d,
                                 float* __restrict__ xs, float* __restrict__ a_src,
                                 float* __restrict__ a_dst, int N){
  int n = blockIdx.x;          // one node per block
  int j = threadIdx.x;         // 0..127 output channel
  __shared__ float sA[K];
  __shared__ float s_s[128], s_d[128];
  if (j < K) sA[j] = A[(size_t)n * K + j];
  __syncthreads();
  float acc = 0.f;
  #pragma unroll
  for (int k = 0; k < K; ++k) acc += sA[k] * W[k * 128 + j];
  xs[(size_t)n * 128 + j] = acc;
  s_s[j] = acc * att_s[j];
  s_d[j] = acc * att_d[j];
  __syncthreads();
  if (j < 4){
    float ss = 0.f, sd = 0.f;
    #pragma unroll
    for (int c = 0; c < 32; ++c){ ss += s_s[j*32 + c]; sd += s_d[j*32 + c]; }
    a_src[n*4 + j] = ss;
    a_dst[n*4 + j] = sd;
  }
}

// ---------------- CSR build ----------------
__global__ void count_kernel(const int* __restrict__ ei, int E, int* __restrict__ cnt){
  int e = blockIdx.x * blockDim.x + threadIdx.x;
  if (e < E) atomicAdd(&cnt[ei[E + e]], 1);   // row 1 = dst
}

__global__ void scan_kernel(const int* __restrict__ cnt, int N, int* __restrict__ rp){
  const int tid = threadIdx.x;
  const int lane = tid & 63;
  const int wv = tid >> 6;              // 0..15 (1024 threads)
  __shared__ int wsum[16];
  __shared__ int carry;
  if (tid == 0){ carry = 0; rp[0] = 0; }
  __syncthreads();
  for (int base = 0; base < N; base += 1024){
    int idx = base + tid;
    int v = (idx < N) ? cnt[idx] : 0;
    int x = v;
    #pragma unroll
    for (int d = 1; d < 64; d <<= 1){
      int y = __shfl_up(x, d);
      if (lane >= d) x += y;
    }
    if (lane == 63) wsum[wv] = x;
    __syncthreads();
    if (tid < 16){
      int y = wsum[tid];
      #pragma unroll
      for (int d = 1; d < 16; d <<= 1){
        int z = __shfl_up(y, d);
        if (tid >= d) y += z;
      }
      wsum[tid] = y;                    // inclusive over wave sums
    }
    __syncthreads();
    int off = carry + (wv > 0 ? wsum[wv-1] : 0);
    int incl = off + x;
    if (idx < N) rp[idx + 1] = incl;
    __syncthreads();
    if (tid == 1023) carry = incl;      // chunk total (tail lanes add 0)
    __syncthreads();
  }
}

__global__ void fill_kernel(const int* __restrict__ ei, const float* __restrict__ eattr, int E,
                            const int* __restrict__ rp, int* __restrict__ fc,
                            int* __restrict__ csrc, float* __restrict__ cea){
  int e = blockIdx.x * blockDim.x + threadIdx.x;
  if (e >= E) return;
  int src = ei[e];
  int dst = ei[E + e];
  int pos = rp[dst] + atomicAdd(&fc[dst], 1);
  csrc[pos] = src;
  if (eattr) cea[pos] = eattr[e];
}

__global__ void loopea_kernel(const int* __restrict__ rp, const float* __restrict__ cea,
                              float* __restrict__ lea, int N){
  int n = blockIdx.x * blockDim.x + threadIdx.x;
  if (n >= N) return;
  int b = rp[n], e = rp[n+1];
  float s = 0.f;
  for (int i = b; i < e; ++i) s += cea[i];
  lea[n] = s / fmaxf((float)(e - b), 1.f);
}

__global__ void coef_kernel(const float* __restrict__ We1, const float* __restrict__ ae1,
                            const float* __restrict__ We2, const float* __restrict__ ae2,
                            float* __restrict__ coef){
  int t = threadIdx.x;
  if (t < 4){
    float s = 0.f;
    for (int c = 0; c < 32; ++c) s += We1[t*32 + c] * ae1[t*32 + c];
    coef[t] = s;
  } else if (t < 8){
    int h = t - 4;
    float s = 0.f;
    for (int c = 0; c < 32; ++c) s += We2[h*32 + c] * ae2[h*32 + c];
    coef[4 + h] = s;
  }
}

// ---------------- GAT per-node kernel: one wave per node ----------------
template<bool HASE, bool RELU>
__global__ void gat_kernel(const int* __restrict__ rp, const int* __restrict__ csrc,
                           const float* __restrict__ cea, const float* __restrict__ loopea,
                           const float* __restrict__ coef,
                           const float* __restrict__ xs, const float* __restrict__ a_src,
                           const float* __restrict__ a_dst, const float* __restrict__ bias,
                           float* __restrict__ out, int N){
  const int wv = threadIdx.x >> 6;
  const int lane = threadIdx.x & 63;
  const int n = blockIdx.x * 4 + wv;
  if (n >= N) return;

  const int beg = rp[n], end = rp[n+1];
  const int deg = end - beg;

  const float4 adv = *reinterpret_cast<const float4*>(a_dst + (size_t)n*4);
  const float4 asv = *reinterpret_cast<const float4*>(a_src + (size_t)n*4);
  float c0 = 0.f, c1 = 0.f, c2 = 0.f, c3 = 0.f, lea = 0.f;
  if (HASE){ c0 = coef[0]; c1 = coef[1]; c2 = coef[2]; c3 = coef[3]; lea = loopea[n]; }

  // self-loop alpha (pre-softmax)
  const float s0 = lrelu(asv.x + adv.x + lea*c0);
  const float s1 = lrelu(asv.y + adv.y + lea*c1);
  const float s2 = lrelu(asv.z + adv.z + lea*c2);
  const float s3 = lrelu(asv.w + adv.w + lea*c3);

  // -------- phase 1: per-head max over incoming edges (lane-parallel) --------
  float m0 = s0, m1 = s1, m2 = s2, m3 = s3;
  for (int i = lane; i < deg; i += 64){
    int s = csrc[beg + i];
    float ea = HASE ? cea[beg + i] : 0.f;
    const float4 av = *reinterpret_cast<const float4*>(a_src + (size_t)s*4);
    m0 = fmaxf(m0, lrelu(av.x + adv.x + ea*c0));
    m1 = fmaxf(m1, lrelu(av.y + adv.y + ea*c1));
    m2 = fmaxf(m2, lrelu(av.z + adv.z + ea*c2));
    m3 = fmaxf(m3, lrelu(av.w + adv.w + ea*c3));
  }
  #pragma unroll
  for (int d = 1; d < 64; d <<= 1){
    m0 = fmaxf(m0, __shfl_xor(m0, d));
    m1 = fmaxf(m1, __shfl_xor(m1, d));
    m2 = fmaxf(m2, __shfl_xor(m2, d));
    m3 = fmaxf(m3, __shfl_xor(m3, d));
  }

  // -------- phase 2: fused exp + denom + aggregation --------
  const int c = lane * 2;           // this lane owns channels c, c+1
  const int h = c >> 5;             // head of those channels
  const float mh  = (h==0) ? m0 : (h==1) ? m1 : (h==2) ? m2 : m3;
  const float adh = (h==0) ? adv.x : (h==1) ? adv.y : (h==2) ? adv.z : adv.w;
  const float ch  = (h==0) ? c0 : (h==1) ? c1 : (h==2) ? c2 : c3;
  const float sh  = (h==0) ? s0 : (h==1) ? s1 : (h==2) ? s2 : s3;

  float ps = expf(sh - mh);
  float denom = ps;
  float2 selfv = *reinterpret_cast<const float2*>(xs + (size_t)n*128 + c);
  float accx = ps * selfv.x;
  float accy = ps * selfv.y;

  for (int i = 0; i < deg; ++i){
    int s = csrc[beg + i];                       // uniform across lanes
    float ea = HASE ? cea[beg + i] : 0.f;
    float a = a_src[(size_t)s*4 + h];
    float al = lrelu(a + adh + ea*ch);
    float p = expf(al - mh);
    denom += p;
    float2 v = *reinterpret_cast<const float2*>(xs + (size_t)s*128 + c);
    accx += p * v.x;
    accy += p * v.y;
  }

  const float inv = 1.f / (denom + 1e-16f);
  float ox = accx * inv + bias[c];
  float oy = accy * inv + bias[c+1];
  if (RELU){ ox = fmaxf(ox, 0.f); oy = fmaxf(oy, 0.f); }
  out[(size_t)n*128 + c]     = ox;
  out[(size_t)n*128 + c + 1] = oy;
}

// ---------------- pooling (sorted-batch segment reduction, few atomics) ----------------
// batch is sorted -> each 32-node chunk spans ~1.05 graph segments. Thread j owns
// channel j; flush one atomicAdd per (segment x channel) instead of per element.
template<bool COUNT>
__global__ void pool_kernel(const float* __restrict__ a, const int* __restrict__ batch,
                            float* __restrict__ sums, int* __restrict__ cnts, int N){
  const int j = threadIdx.x;                 // channel 0..127
  const int n0 = blockIdx.x * 32;
  const int n1 = min(n0 + 32, N);
  if (n0 >= N) return;
  int g = batch[n0];
  float acc = 0.f;
  int cnt = 0;
  for (int n = n0; n < n1; ++n){
    int gn = batch[n];                       // broadcast load (same addr all lanes)
    if (gn != g){                            // uniform branch across block
      atomicAdd(&sums[g*128 + j], 0.5f * acc);
      if (COUNT && j == 0) atomicAdd(&cnts[g], cnt);
      acc = 0.f; cnt = 0; g = gn;
    }
    acc += a[(size_t)n*128 + j];
    ++cnt;
  }
  atomicAdd(&sums[g*128 + j], 0.5f * acc);
  if (COUNT && j == 0) atomicAdd(&cnts[g], cnt);
}

__global__ void head_kernel(const float* __restrict__ sums, const int* __restrict__ cnts,
                            const float* __restrict__ ffW, const float* __restrict__ ffb,
                            const float* __restrict__ outW, const float* __restrict__ outb,
                            float* __restrict__ out){
  int g = blockIdx.x, j = threadIdx.x;   // 64 blocks x 128 threads
  __shared__ float mean[128];
  __shared__ float red[128];
  float cnt = fmaxf((float)cnts[g], 1.f);
  mean[j] = sums[g*128 + j] / cnt;
  __syncthreads();
  float acc = ffb[j];
  #pragma unroll 8
  for (int k = 0; k < 128; ++k) acc += mean[k] * ffW[k*128 + j];
  acc = fmaxf(acc, 0.f);
  red[j] = acc * outW[j];
  __syncthreads();
  for (int s = 64; s > 0; s >>= 1){
    if (j < s) red[j] += red[j + s];
    __syncthreads();
  }
  if (j == 0) out[g] = 1.f / (1.f + expf(-(red[0] + outb[0])));
}

// ---------------- host launch ----------------
extern "C" void kernel_launch(void* const* d_in, const int* in_sizes, int n_in,
                              void* d_out, int out_size, void* d_ws, size_t ws_size,
                              hipStream_t stream) {
  const float* x     = (const float*)d_in[0];
  const int*   cov   = (const int*)d_in[1];
  const int*   dist  = (const int*)d_in[2];
  const float* dattr = (const float*)d_in[3];
  const int*   batch = (const int*)d_in[4];
  const float* W_c1 = (const float*)d_in[5],  *as_c1 = (const float*)d_in[6],
             *ad_c1 = (const float*)d_in[7],  *b_c1  = (const float*)d_in[8];
  const float* W_c2 = (const float*)d_in[9],  *as_c2 = (const float*)d_in[10],
             *ad_c2 = (const float*)d_in[11], *b_c2  = (const float*)d_in[12];
  const float* W_d1 = (const float*)d_in[13], *as_d1 = (const float*)d_in[14],
             *ad_d1 = (const float*)d_in[15], *b_d1  = (const float*)d_in[16];
  const float* W_d2 = (const float*)d_in[17], *as_d2 = (const float*)d_in[18],
             *ad_d2 = (const float*)d_in[19], *b_d2  = (const float*)d_in[20];
  const float* We_d1 = (const float*)d_in[21], *ae_d1 = (const float*)d_in[22];
  const float* We_d2 = (const float*)d_in[23], *ae_d2 = (const float*)d_in[24];
  const float* ffW = (const float*)d_in[25], *ffb = (const float*)d_in[26];
  const float* outW = (const float*)d_in[27], *outb = (const float*)d_in[28];
  float* out = (float*)d_out;

  const int N  = in_sizes[0] / 32;
  const int Ec = in_sizes[1] / 2;
  const int Ed = in_sizes[2] / 2;

  char* p = (char*)d_ws;
  auto alloc = [&](size_t bytes) -> void* {
    void* r = (void*)p;
    p += (bytes + 255) & ~(size_t)255;
    return r;
  };
  float* act    = (float*)alloc((size_t)N * 128 * 4);
  float* xs     = (float*)alloc((size_t)N * 128 * 4);
  float* a_s    = (float*)alloc((size_t)N * 4 * 4);
  float* a_d    = (float*)alloc((size_t)N * 4 * 4);
  int*   rp_c   = (int*)alloc((size_t)(N + 1) * 4);
  int*   rp_d   = (int*)alloc((size_t)(N + 1) * 4);
  int*   csrc_c = (int*)alloc((size_t)Ec * 4);
  int*   csrc_d = (int*)alloc((size_t)Ed * 4);
  float* cea_d  = (float*)alloc((size_t)Ed * 4);
  int*   cnt    = (int*)alloc((size_t)N * 4);
  float* lea    = (float*)alloc((size_t)N * 4);
  float* coef   = (float*)alloc(8 * 4);
  float* sums   = (float*)alloc(64 * 128 * 4);
  int*   cnts   = (int*)alloc(64 * 4);

  const int TB = 256;
  // ---- covalent CSR ----
  hipMemsetAsync(cnt, 0, (size_t)N * 4, stream);
  count_kernel<<<(Ec + TB - 1) / TB, TB, 0, stream>>>(cov, Ec, cnt);
  scan_kernel<<<1, 1024, 0, stream>>>(cnt, N, rp_c);
  hipMemsetAsync(cnt, 0, (size_t)N * 4, stream);
  fill_kernel<<<(Ec + TB - 1) / TB, TB, 0, stream>>>(cov, nullptr, Ec, rp_c, cnt, csrc_c, nullptr);
  // ---- distance CSR ----
  hipMemsetAsync(cnt, 0, (size_t)N * 4, stream);
  count_kernel<<<(Ed + TB - 1) / TB, TB, 0, stream>>>(dist, Ed, cnt);
  scan_kernel<<<1, 1024, 0, stream>>>(cnt, N, rp_d);
  hipMemsetAsync(cnt, 0, (size_t)N * 4, stream);
  fill_kernel<<<(Ed + TB - 1) / TB, TB, 0, stream>>>(dist, dattr, Ed, rp_d, cnt, csrc_d, cea_d);
  loopea_kernel<<<(N + TB - 1) / TB, TB, 0, stream>>>(rp_d, cea_d, lea, N);
  coef_kernel<<<1, 64, 0, stream>>>(We_d1, ae_d1, We_d2, ae_d2, coef);

  hipMemsetAsync(sums, 0, 64 * 128 * 4, stream);
  hipMemsetAsync(cnts, 0, 64 * 4, stream);

  const int gatGrid = (N + 3) / 4;
  const int poolGrid = (N + 31) / 32;
  // ---- covalent branch ----
  transform_kernel<32><<<N, 128, 0, stream>>>(x, W_c1, as_c1, ad_c1, xs, a_s, a_d, N);
  gat_kernel<false, true><<<gatGrid, 256, 0, stream>>>(rp_c, csrc_c, nullptr, nullptr, nullptr,
                                                       xs, a_s, a_d, b_c1, act, N);
  transform_kernel<128><<<N, 128, 0, stream>>>(act, W_c2, as_c2, ad_c2, xs, a_s, a_d, N);
  gat_kernel<false, false><<<gatGrid, 256, 0, stream>>>(rp_c, csrc_c, nullptr, nullptr, nullptr,
                                                        xs, a_s, a_d, b_c2, act, N);
  pool_kernel<true><<<poolGrid, 128, 0, stream>>>(act, batch, sums, cnts, N);
  // ---- distance branch ----
  transform_kernel<32><<<N, 128, 0, stream>>>(x, W_d1, as_d1, ad_d1, xs, a_s, a_d, N);
  gat_kernel<true, true><<<gatGrid, 256, 0, stream>>>(rp_d, csrc_d, cea_d, lea, coef,
                                                      xs, a_s, a_d, b_d1, act, N);
  transform_kernel<128><<<N, 128, 0, stream>>>(act, W_d2, as_d2, ad_d2, xs, a_s, a_d, N);
  gat_kernel<true, false><<<gatGrid, 256, 0, stream>>>(rp_d, csrc_d, cea_d, lea, coef + 4,
                                                       xs, a_s, a_d, b_d2, act, N);
  pool_kernel<false><<<poolGrid, 128, 0, stream>>>(act, batch, sums, nullptr, N);
  // ---- head ----
  head_kernel<<<64, 128, 0, stream>>>(sums, cnts, ffW, ffb, outW, outb, out);
}